// Round 1
// baseline (966.274 us; speedup 1.0000x reference)
//
#include <hip/hip_runtime.h>
#include <cstddef>

// Problem shape (fixed by setup_inputs): B=32, S=8192, D=512, fp32.
#define BATCH 32
#define SEQ   8192
#define DIM   512
#define NEG_INF_F (-1e9f)

// PV partial split over S
#define NCHUNK 64
#define SCHUNK (SEQ / NCHUNK)   // 128

// ---------------------------------------------------------------------------
// Kernel 1: scores[b,s] = dot(q[b,:], k[b,s,:])  (masked)
// One wave (64 lanes) per row; lane handles 8 contiguous floats (2 float4).
// ---------------------------------------------------------------------------
__global__ __launch_bounds__(256) void scores_kernel(
    const float* __restrict__ q, const float* __restrict__ k,
    const int* __restrict__ mask, float* __restrict__ score) {
  const int wave = threadIdx.x >> 6;          // 0..3
  const int lane = threadIdx.x & 63;
  const size_t row = (size_t)blockIdx.x * 4 + wave;   // 0 .. B*S-1
  const int b = (int)(row >> 13);             // / 8192
  const int s = (int)(row & (SEQ - 1));

  const float4* __restrict__ krow = (const float4*)(k + row * DIM);
  const float4* __restrict__ qrow = (const float4*)(q + (size_t)b * DIM);

  const int i0 = lane * 2;
  float4 k0 = krow[i0];
  float4 k1 = krow[i0 + 1];
  float4 q0 = qrow[i0];
  float4 q1 = qrow[i0 + 1];

  float d = k0.x * q0.x + k0.y * q0.y + k0.z * q0.z + k0.w * q0.w
          + k1.x * q1.x + k1.y * q1.y + k1.z * q1.z + k1.w * q1.w;

  #pragma unroll
  for (int off = 32; off > 0; off >>= 1) d += __shfl_down(d, off, 64);

  if (lane == 0) {
    float sc = (mask[(size_t)b * SEQ + s] == 0) ? NEG_INF_F : d;
    score[row] = sc;
  }
}

// ---------------------------------------------------------------------------
// Kernel 2: in-place softmax over S per batch. One block (256 thr) per batch.
// ---------------------------------------------------------------------------
__global__ __launch_bounds__(256) void softmax_kernel(float* __restrict__ score) {
  __shared__ float red[4];
  const int b = blockIdx.x;
  float* __restrict__ sc = score + (size_t)b * SEQ;
  const int tid = threadIdx.x;

  float vals[SEQ / 256];   // 32 per thread
  float lmax = -3.0e38f;
  #pragma unroll
  for (int i = 0; i < SEQ / 256; ++i) {
    vals[i] = sc[tid + i * 256];
    lmax = fmaxf(lmax, vals[i]);
  }
  #pragma unroll
  for (int off = 32; off > 0; off >>= 1)
    lmax = fmaxf(lmax, __shfl_down(lmax, off, 64));
  if ((tid & 63) == 0) red[tid >> 6] = lmax;
  __syncthreads();
  const float m = fmaxf(fmaxf(red[0], red[1]), fmaxf(red[2], red[3]));
  __syncthreads();   // protect red[] before reuse

  float lsum = 0.0f;
  #pragma unroll
  for (int i = 0; i < SEQ / 256; ++i) {
    vals[i] = __expf(vals[i] - m);
    lsum += vals[i];
  }
  #pragma unroll
  for (int off = 32; off > 0; off >>= 1) lsum += __shfl_down(lsum, off, 64);
  if ((tid & 63) == 0) red[tid >> 6] = lsum;
  __syncthreads();
  const float inv = 1.0f / (red[0] + red[1] + red[2] + red[3]);

  #pragma unroll
  for (int i = 0; i < SEQ / 256; ++i) sc[tid + i * 256] = vals[i] * inv;
}

// ---------------------------------------------------------------------------
// Kernel 3: partial PV. Block = (b, s-chunk of 128); 128 threads, each owns
// one float4 column of D. Probs staged in LDS. Deterministic partials to ws.
// ---------------------------------------------------------------------------
__global__ __launch_bounds__(128) void pv_kernel(
    const float* __restrict__ p, const float* __restrict__ v,
    float* __restrict__ part) {
  __shared__ float pl[SCHUNK];
  const int b = blockIdx.x / NCHUNK;
  const int c = blockIdx.x % NCHUNK;
  const int tid = threadIdx.x;           // 0..127
  const int s0 = c * SCHUNK;

  pl[tid] = p[(size_t)b * SEQ + s0 + tid];
  __syncthreads();

  const float4* __restrict__ vbase =
      (const float4*)(v + ((size_t)b * SEQ + s0) * DIM);
  float4 acc = {0.f, 0.f, 0.f, 0.f};
  #pragma unroll 4
  for (int i = 0; i < SCHUNK; ++i) {
    float4 vv = vbase[(size_t)i * (DIM / 4) + tid];
    float ps = pl[i];
    acc.x += ps * vv.x;
    acc.y += ps * vv.y;
    acc.z += ps * vv.z;
    acc.w += ps * vv.w;
  }
  ((float4*)part)[((size_t)c * BATCH + b) * (DIM / 4) + tid] = acc;
}

// ---------------------------------------------------------------------------
// Kernel 4: reduce partials over NCHUNK -> out[b,d]
// ---------------------------------------------------------------------------
__global__ __launch_bounds__(256) void reduce_kernel(
    const float* __restrict__ part, float* __restrict__ out) {
  const int idx = blockIdx.x * 256 + threadIdx.x;   // over B*D/4 float4s
  const float4* __restrict__ p4 = (const float4*)part;
  float4 acc = {0.f, 0.f, 0.f, 0.f};
  #pragma unroll 8
  for (int c = 0; c < NCHUNK; ++c) {
    float4 t = p4[(size_t)c * (BATCH * DIM / 4) + idx];
    acc.x += t.x; acc.y += t.y; acc.z += t.z; acc.w += t.w;
  }
  ((float4*)out)[idx] = acc;
}

// ---------------------------------------------------------------------------
extern "C" void kernel_launch(void* const* d_in, const int* in_sizes, int n_in,
                              void* d_out, int out_size, void* d_ws, size_t ws_size,
                              hipStream_t stream) {
  const float* q    = (const float*)d_in[0];   // [B, D]
  const float* k    = (const float*)d_in[1];   // [B, S, D]
  const float* v    = (const float*)d_in[2];   // [B, S, D]
  const int*   mask = (const int*)d_in[3];     // [B, 1, S]
  float* out = (float*)d_out;                  // [B, D]

  // Workspace layout: scores/probs (B*S floats = 1 MB), partials (NCHUNK*B*D floats = 4 MB)
  float* score = (float*)d_ws;
  float* part  = score + (size_t)BATCH * SEQ;

  // 1) scores: B*S rows / 4 rows per block
  scores_kernel<<<BATCH * SEQ / 4, 256, 0, stream>>>(q, k, mask, score);
  // 2) softmax per batch (in place)
  softmax_kernel<<<BATCH, 256, 0, stream>>>(score);
  // 3) partial PV
  pv_kernel<<<BATCH * NCHUNK, 128, 0, stream>>>(score, v, part);
  // 4) reduce partials -> out
  reduce_kernel<<<BATCH * DIM / 4 / 256, 256, 0, stream>>>(part, out);
}